// Round 1
// baseline (688.307 us; speedup 1.0000x reference)
//
#include <hip/hip_runtime.h>

#define HIDDEN 1024
#define EXPD   256
#define NH     16
#define HD     64
#define BB     4
#define SS     2048
#define NTOK   (BB*SS)   /* 8192 */
#define NCAT   3584      /* 3*1024 + 2*256 */

typedef __attribute__((ext_vector_type(8))) short short8;
typedef __attribute__((ext_vector_type(4))) float f32x4;

__device__ __forceinline__ unsigned short f2b(float f) {
  unsigned int u = __float_as_uint(f);
  u += 0x7fffu + ((u >> 16) & 1u);
  return (unsigned short)(u >> 16);
}
__device__ __forceinline__ float b2f(unsigned short u) {
  return __uint_as_float(((unsigned int)u) << 16);
}
__device__ __forceinline__ f32x4 mfma_bf16(short8 a, short8 b, f32x4 c) {
  return __builtin_amdgcn_mfma_f32_16x16x32_bf16(a, b, c, 0, 0, 0);
}

// ---- prep: x -> [xh | xl] bf16, row-major [8192][2048] ------------------
__global__ __launch_bounds__(256) void prep_x(const float* __restrict__ x,
                                              unsigned short* __restrict__ A1) {
  const int idx4 = (blockIdx.x * 256 + threadIdx.x) * 4;
  const float4 xv = *reinterpret_cast<const float4*>(&x[idx4]);
  const int token = idx4 >> 10, c = idx4 & 1023;
  float vs[4] = {xv.x, xv.y, xv.z, xv.w};
  unsigned short hi[4], lo[4];
#pragma unroll
  for (int e = 0; e < 4; ++e) {
    unsigned short h = f2b(vs[e]);
    hi[e] = h;
    lo[e] = f2b(vs[e] - b2f(h));
  }
  uint2 hv, lv;
  hv.x = (unsigned int)hi[0] | ((unsigned int)hi[1] << 16);
  hv.y = (unsigned int)hi[2] | ((unsigned int)hi[3] << 16);
  lv.x = (unsigned int)lo[0] | ((unsigned int)lo[1] << 16);
  lv.y = (unsigned int)lo[2] | ((unsigned int)lo[3] << 16);
  *reinterpret_cast<uint2*>(&A1[token * 2048 + c]) = hv;
  *reinterpret_cast<uint2*>(&A1[token * 2048 + 1024 + c]) = lv;
}

// ---- concat biases into bcat[3584] --------------------------------------
__global__ void bias_cat(const float* __restrict__ bq, const float* __restrict__ bk,
                         const float* __restrict__ bv, const float* __restrict__ beq,
                         const float* __restrict__ bek, float* __restrict__ bcat) {
  const int n = blockIdx.x * 256 + threadIdx.x;
  if (n >= NCAT) return;
  float v;
  if (n < 1024) v = bq[n];
  else if (n < 2048) v = bk[n - 1024];
  else if (n < 3072) v = bv[n - 2048];
  else if (n < 3328) v = beq[n - 3072];
  else v = bek[n - 3328];
  bcat[n] = v;
}

// ---- transpose f32 weight [1024][C] -> bf16 dst[n][k] (B^T layout) ------
// if dup: also write at k+1024 (for the 2-term split GEMM)
__global__ __launch_bounds__(256) void trans_w(const float* __restrict__ src, int C,
                                               unsigned short* __restrict__ dst, int dstld,
                                               int n_off, int dup) {
  __shared__ unsigned short t[64 * 68];
  const int k0 = blockIdx.x * 64, c0 = blockIdx.y * 64;
  const int tid = threadIdx.x;
#pragma unroll
  for (int i = 0; i < 16; ++i) {
    int e = i * 256 + tid;
    int r = e >> 6, c = e & 63;
    t[r * 68 + c] = f2b(src[(k0 + r) * C + c0 + c]);
  }
  __syncthreads();
#pragma unroll
  for (int i = 0; i < 16; ++i) {
    int e = i * 256 + tid;
    int r2 = e >> 6, c2 = e & 63;  // r2 = n index, c2 = k index
    unsigned short v = t[c2 * 68 + r2];
    dst[(n_off + c0 + r2) * dstld + k0 + c2] = v;
    if (dup) dst[(n_off + c0 + r2) * dstld + 1024 + k0 + c2] = v;
  }
}

// ---- transpose V columns of QKVEE -> Vt[hd_global][token] ---------------
__global__ __launch_bounds__(256) void trans_v(const unsigned short* __restrict__ QKVEE,
                                               unsigned short* __restrict__ Vt) {
  __shared__ unsigned short t[64 * 68];
  const int tok0 = blockIdx.x * 64, hc0 = blockIdx.y * 64;
  const int tid = threadIdx.x;
#pragma unroll
  for (int i = 0; i < 16; ++i) {
    int e = i * 256 + tid;
    int r = e >> 6, c = e & 63;  // r = token, c = hc
    t[r * 68 + c] = QKVEE[(long long)(tok0 + r) * NCAT + 2048 + hc0 + c];
  }
  __syncthreads();
#pragma unroll
  for (int i = 0; i < 16; ++i) {
    int e = i * 256 + tid;
    int r2 = e >> 6, c2 = e & 63;  // r2 = hc, c2 = token
    Vt[(long long)(hc0 + r2) * NTOK + tok0 + c2] = t[c2 * 68 + r2];
  }
}

// ---- generic 128x128 MFMA GEMM, A[M,K] bf16 row-major, Bt[N,K] bf16 -----
// MODE 0: bf16 out = acc + bias[col]
// MODE 1: bf16 out = acc * scale
// MODE 2: f32  out = acc + bias[col]
template <int MODE>
__global__ __launch_bounds__(256) void gemm128(
    const unsigned short* __restrict__ A, long long sAz, int lda,
    const unsigned short* __restrict__ Bt, long long sBz, int ldb,
    void* __restrict__ Cv, long long sCz, int ldc,
    const float* __restrict__ bias, float scale, int K) {
  __shared__ __align__(16) unsigned short As[128 * 64];
  __shared__ __align__(16) unsigned short Bs[128 * 64];
  const int tid = threadIdx.x;
  const int lane = tid & 63, w = tid >> 6;
  const int wm = (w >> 1) * 64, wn = (w & 1) * 64;
  const int m0 = blockIdx.x * 128, n0 = blockIdx.y * 128;
  const int z = blockIdx.z;
  A += (long long)z * sAz;
  Bt += (long long)z * sBz;

  f32x4 acc[4][4];
#pragma unroll
  for (int i = 0; i < 4; ++i)
#pragma unroll
    for (int j = 0; j < 4; ++j)
#pragma unroll
      for (int e = 0; e < 4; ++e) acc[i][j][e] = 0.0f;

  const int er = (tid * 8) >> 6;  // 0..31
  const int ec = (tid * 8) & 63;

  for (int k0 = 0; k0 < K; k0 += 64) {
    short8 av[4], bv[4];
#pragma unroll
    for (int i = 0; i < 4; ++i) {
      av[i] = *reinterpret_cast<const short8*>(&A[(long long)(m0 + er + i * 32) * lda + k0 + ec]);
      bv[i] = *reinterpret_cast<const short8*>(&Bt[(long long)(n0 + er + i * 32) * ldb + k0 + ec]);
    }
    __syncthreads();
#pragma unroll
    for (int i = 0; i < 4; ++i) {
      *reinterpret_cast<short8*>(&As[(er + i * 32) * 64 + ec]) = av[i];
      *reinterpret_cast<short8*>(&Bs[(er + i * 32) * 64 + ec]) = bv[i];
    }
    __syncthreads();
#pragma unroll
    for (int kk = 0; kk < 2; ++kk) {
      const int ko = kk * 32 + (lane >> 4) * 8;
      short8 af[4], bf[4];
#pragma unroll
      for (int mf = 0; mf < 4; ++mf)
        af[mf] = *reinterpret_cast<const short8*>(&As[(wm + mf * 16 + (lane & 15)) * 64 + ko]);
#pragma unroll
      for (int nf = 0; nf < 4; ++nf)
        bf[nf] = *reinterpret_cast<const short8*>(&Bs[(wn + nf * 16 + (lane & 15)) * 64 + ko]);
#pragma unroll
      for (int mf = 0; mf < 4; ++mf)
#pragma unroll
        for (int nf = 0; nf < 4; ++nf)
          acc[mf][nf] = mfma_bf16(af[mf], bf[nf], acc[mf][nf]);
    }
  }

  // C layout: col = lane&15, row = (lane>>4)*4 + j   [guide m89-verified]
  const int rb = m0 + wm + ((lane >> 4) << 2);
  const int cb = n0 + wn + (lane & 15);
#pragma unroll
  for (int mf = 0; mf < 4; ++mf) {
#pragma unroll
    for (int nf = 0; nf < 4; ++nf) {
      const int col = cb + nf * 16;
#pragma unroll
      for (int j = 0; j < 4; ++j) {
        const int row = rb + mf * 16 + j;
        const float v = acc[mf][nf][j];
        if (MODE == 0) {
          unsigned short* C = (unsigned short*)Cv + (long long)z * sCz;
          C[(long long)row * ldc + col] = f2b(v + bias[col]);
        } else if (MODE == 1) {
          unsigned short* C = (unsigned short*)Cv + (long long)z * sCz;
          C[(long long)row * ldc + col] = f2b(v * scale);
        } else {
          float* C = (float*)Cv + (long long)z * sCz;
          C[(long long)row * ldc + col] = v + bias[col];
        }
      }
    }
  }
}

// ---- fused flash attention with shared additive bias --------------------
// grid (32 q-tiles, 16 heads, 4 batch); 4 waves, each owns 16 q-rows.
__global__ __launch_bounds__(256) void attn_kernel(
    const unsigned short* __restrict__ QKVEE,
    const unsigned short* __restrict__ Vt,
    const unsigned short* __restrict__ expS,
    const float* __restrict__ conf,
    unsigned short* __restrict__ ctx) {
  __shared__ __align__(16) unsigned short Qs[64 * 64];
  __shared__ __align__(16) unsigned short Ks[64 * 64];
  __shared__ __align__(16) unsigned short Vts[64 * 72];
  __shared__ __align__(16) unsigned short Bsb[64 * 64];
  __shared__ __align__(16) unsigned short Pl[4][16 * 72];

  const int tid = threadIdx.x, lane = tid & 63, w = tid >> 6;
  const int qt = blockIdx.x, h = blockIdx.y, b = blockIdx.z;
  const int qbase = qt * 64;
  const long long tb = (long long)b * SS;
  const float cbias = 0.3f * conf[b];

  const int sr = tid >> 3;         // 0..31
  const int sc = (tid & 7) * 8;    // 0..56

  // Q tile [64 q][64 d]
#pragma unroll
  for (int i = 0; i < 2; ++i) {
    short8 v = *reinterpret_cast<const short8*>(
        &QKVEE[(tb + qbase + sr + i * 32) * NCAT + h * HD + sc]);
    *reinterpret_cast<short8*>(&Qs[(sr + i * 32) * 64 + sc]) = v;
  }

  float m[4], l[4];
  f32x4 acc[4];
#pragma unroll
  for (int j = 0; j < 4; ++j) { m[j] = -3.0e38f; l[j] = 0.0f; }
#pragma unroll
  for (int nf = 0; nf < 4; ++nf)
#pragma unroll
    for (int j = 0; j < 4; ++j) acc[nf][j] = 0.0f;

  for (int kb = 0; kb < SS; kb += 64) {
    short8 kv[2], vv[2], bb2[2];
#pragma unroll
    for (int i = 0; i < 2; ++i) {
      kv[i] = *reinterpret_cast<const short8*>(
          &QKVEE[(tb + kb + sr + i * 32) * NCAT + HIDDEN + h * HD + sc]);
      vv[i] = *reinterpret_cast<const short8*>(
          &Vt[(long long)(h * HD + sr + i * 32) * NTOK + tb + kb + sc]);
      bb2[i] = *reinterpret_cast<const short8*>(
          &expS[(tb + qbase + sr + i * 32) * SS + kb + sc]);
    }
    __syncthreads();
#pragma unroll
    for (int i = 0; i < 2; ++i) {
      *reinterpret_cast<short8*>(&Ks[(sr + i * 32) * 64 + sc]) = kv[i];
      *reinterpret_cast<short8*>(&Vts[(sr + i * 32) * 72 + sc]) = vv[i];
      *reinterpret_cast<short8*>(&Bsb[(sr + i * 32) * 64 + sc]) = bb2[i];
    }
    __syncthreads();

    // S = Q K^T  (wave strip: [16 q][64 k])
    f32x4 s[4];
#pragma unroll
    for (int nf = 0; nf < 4; ++nf)
#pragma unroll
      for (int j = 0; j < 4; ++j) s[nf][j] = 0.0f;
#pragma unroll
    for (int kk = 0; kk < 2; ++kk) {
      const int ko = kk * 32 + (lane >> 4) * 8;
      short8 aq = *reinterpret_cast<const short8*>(&Qs[(w * 16 + (lane & 15)) * 64 + ko]);
#pragma unroll
      for (int nf = 0; nf < 4; ++nf) {
        short8 bk = *reinterpret_cast<const short8*>(&Ks[(nf * 16 + (lane & 15)) * 64 + ko]);
        s[nf] = mfma_bf16(aq, bk, s[nf]);
      }
    }

    // scale + shared bias; C layout: col=lane&15, row=(lane>>4)*4+j
    const int r0 = (lane >> 4) * 4;
    const int c0 = lane & 15;
    float sv[4][4];
#pragma unroll
    for (int nf = 0; nf < 4; ++nf)
#pragma unroll
      for (int j = 0; j < 4; ++j) {
        const int qrow = w * 16 + r0 + j;
        sv[nf][j] = s[nf][j] * 0.125f + cbias * b2f(Bsb[qrow * 64 + nf * 16 + c0]);
      }

    // row max across 64 keys (4 frags in-lane, then 16 lanes)
    float rmax[4];
#pragma unroll
    for (int j = 0; j < 4; ++j)
      rmax[j] = fmaxf(fmaxf(sv[0][j], sv[1][j]), fmaxf(sv[2][j], sv[3][j]));
#pragma unroll
    for (int mask = 1; mask <= 8; mask <<= 1)
#pragma unroll
      for (int j = 0; j < 4; ++j)
        rmax[j] = fmaxf(rmax[j], __shfl_xor(rmax[j], mask));

    float scl[4];
#pragma unroll
    for (int j = 0; j < 4; ++j) {
      const float mn = fmaxf(m[j], rmax[j]);
      scl[j] = __expf(m[j] - mn);
      m[j] = mn;
    }

    float psum[4] = {0.f, 0.f, 0.f, 0.f};
#pragma unroll
    for (int nf = 0; nf < 4; ++nf)
#pragma unroll
      for (int j = 0; j < 4; ++j) {
        const float p = __expf(sv[nf][j] - m[j]);
        psum[j] += p;
        Pl[w][(r0 + j) * 72 + nf * 16 + c0] = f2b(p);
      }
#pragma unroll
    for (int mask = 1; mask <= 8; mask <<= 1)
#pragma unroll
      for (int j = 0; j < 4; ++j)
        psum[j] += __shfl_xor(psum[j], mask);
#pragma unroll
    for (int j = 0; j < 4; ++j) l[j] = l[j] * scl[j] + psum[j];
#pragma unroll
    for (int nf = 0; nf < 4; ++nf)
#pragma unroll
      for (int j = 0; j < 4; ++j) acc[nf][j] *= scl[j];

    // PV: ctx[16 q][64 d] += P[16,64] @ V[64,64]
#pragma unroll
    for (int kk = 0; kk < 2; ++kk) {
      const int ko = kk * 32 + (lane >> 4) * 8;
      short8 ap = *reinterpret_cast<const short8*>(&Pl[w][(lane & 15) * 72 + ko]);
#pragma unroll
      for (int nf = 0; nf < 4; ++nf) {
        short8 bvv = *reinterpret_cast<const short8*>(&Vts[(nf * 16 + (lane & 15)) * 72 + ko]);
        acc[nf] = mfma_bf16(ap, bvv, acc[nf]);
      }
    }
  }

#pragma unroll
  for (int nf = 0; nf < 4; ++nf)
#pragma unroll
    for (int j = 0; j < 4; ++j) {
      const int qrow = qbase + w * 16 + (lane >> 4) * 4 + j;
      const int d = nf * 16 + (lane & 15);
      ctx[(tb + qrow) * HIDDEN + h * HD + d] = f2b(acc[nf][j] / l[j]);
    }
}

extern "C" void kernel_launch(void* const* d_in, const int* in_sizes, int n_in,
                              void* d_out, int out_size, void* d_ws, size_t ws_size,
                              hipStream_t stream) {
  const float* x    = (const float*)d_in[0];
  const float* conf = (const float*)d_in[1];
  const float* Wq   = (const float*)d_in[2];
  const float* bq   = (const float*)d_in[3];
  const float* Wk   = (const float*)d_in[4];
  const float* bk   = (const float*)d_in[5];
  const float* Wv   = (const float*)d_in[6];
  const float* bv   = (const float*)d_in[7];
  const float* Weq  = (const float*)d_in[8];
  const float* beq  = (const float*)d_in[9];
  const float* Wek  = (const float*)d_in[10];
  const float* bek  = (const float*)d_in[11];
  const float* Wo   = (const float*)d_in[12];
  const float* bo   = (const float*)d_in[13];

  char* ws = (char*)d_ws;
  unsigned short* A1    = (unsigned short*)(ws);                               // 33,554,432 B
  unsigned short* WcatT = (unsigned short*)(ws + 33554432);                    // 14,680,064 B
  float*          bcat  = (float*)(ws + 48234496);                             //     16,384 B (padded)
  unsigned short* WoT   = (unsigned short*)(ws + 48250880);                    //  2,097,152 B
  unsigned short* QKVEE = (unsigned short*)(ws + 50348032);                    // 58,720,256 B
  unsigned short* Vt    = (unsigned short*)(ws + 109068288);                   // 16,777,216 B
  unsigned short* ctx   = (unsigned short*)(ws + 125845504);                   // 16,777,216 B
  // exp-scores (bf16, 33,554,432 B) lives in d_out; overwritten by final GEMM.
  unsigned short* expS  = (unsigned short*)d_out;

  prep_x<<<dim3(8192), dim3(256), 0, stream>>>(x, A1);
  bias_cat<<<dim3(14), dim3(256), 0, stream>>>(bq, bk, bv, beq, bek, bcat);
  trans_w<<<dim3(16, 16), dim3(256), 0, stream>>>(Wq, 1024, WcatT, 2048, 0, 1);
  trans_w<<<dim3(16, 16), dim3(256), 0, stream>>>(Wk, 1024, WcatT, 2048, 1024, 1);
  trans_w<<<dim3(16, 16), dim3(256), 0, stream>>>(Wv, 1024, WcatT, 2048, 2048, 1);
  trans_w<<<dim3(16, 4),  dim3(256), 0, stream>>>(Weq, 256, WcatT, 2048, 3072, 1);
  trans_w<<<dim3(16, 4),  dim3(256), 0, stream>>>(Wek, 256, WcatT, 2048, 3328, 1);
  trans_w<<<dim3(16, 16), dim3(256), 0, stream>>>(Wo, 1024, WoT, 1024, 0, 0);

  // Q|K|V|EQ|EK = [xh|xl] @ [W;W] + bias  (2-term fp32-emulation via bf16 MFMA)
  gemm128<0><<<dim3(64, 28), dim3(256), 0, stream>>>(
      A1, 0, 2048, WcatT, 0, 2048, QKVEE, 0, NCAT, bcat, 1.0f, 2048);

  trans_v<<<dim3(128, 16), dim3(256), 0, stream>>>(QKVEE, Vt);

  // exp_scores[b] = (EQ @ EK^T) / 16  -> bf16 in d_out
  gemm128<1><<<dim3(16, 16, 4), dim3(256), 0, stream>>>(
      QKVEE + 3072, (long long)SS * NCAT, NCAT,
      QKVEE + 3328, (long long)SS * NCAT, NCAT,
      expS, (long long)SS * SS, SS, nullptr, 1.0f / 16.0f, 256);

  attn_kernel<<<dim3(32, 16, 4), dim3(256), 0, stream>>>(QKVEE, Vt, expS, conf, ctx);

  // out = ctx @ Wo + bo  (fp32 out, overwrites exp-scores scratch)
  gemm128<2><<<dim3(64, 8), dim3(256), 0, stream>>>(
      ctx, 0, 1024, WoT, 0, 1024, d_out, 0, 1024, bo, 1.0f, 1024);
}

// Round 2
// 621.541 us; speedup vs baseline: 1.1074x; 1.1074x over previous
//
#include <hip/hip_runtime.h>

#define HIDDEN 1024
#define EXPD   256
#define NH     16
#define HD     64
#define BB     4
#define SS     2048
#define NTOK   (BB*SS)   /* 8192 */
#define NCAT   3584      /* 3*1024 + 2*256 */

typedef __attribute__((ext_vector_type(8))) short short8;
typedef __attribute__((ext_vector_type(4))) float f32x4;
typedef __attribute__((ext_vector_type(4))) unsigned short us4;

__device__ __forceinline__ unsigned short f2b(float f) {
  unsigned int u = __float_as_uint(f);
  u += 0x7fffu + ((u >> 16) & 1u);
  return (unsigned short)(u >> 16);
}
__device__ __forceinline__ float b2f(unsigned short u) {
  return __uint_as_float(((unsigned int)u) << 16);
}
__device__ __forceinline__ f32x4 mfma_bf16(short8 a, short8 b, f32x4 c) {
  return __builtin_amdgcn_mfma_f32_16x16x32_bf16(a, b, c, 0, 0, 0);
}

// async global->LDS, 16B per lane. LDS dest: wave-uniform base + lane*16.
__device__ __forceinline__ void gll16(const unsigned short* g, unsigned short* l) {
  __builtin_amdgcn_global_load_lds(
      (const __attribute__((address_space(1))) void*)g,
      (__attribute__((address_space(3))) void*)l, 16, 0, 0);
}

// swizzled 16B LDS read: logical (row, 16B-block bx) of a [*][64]-short tile
__device__ __forceinline__ short8 lds16(const unsigned short* base, int row, int bx) {
  return *reinterpret_cast<const short8*>(base + row * 64 + ((bx ^ (row & 7)) << 3));
}

// stage a 64x64-short tile from row-major global into swizzled LDS.
// storage slot (lane&7) of row r holds logical block (lane&7)^(r&7)  [m173 pattern]
__device__ __forceinline__ void stage64(const unsigned short* __restrict__ src,
                                        long long ldg, unsigned short* lds,
                                        int w, int lane) {
#pragma unroll
  for (int t = 0; t < 2; ++t) {
    const int rr = w * 16 + t * 8 + (lane >> 3);
    const int cc = ((lane & 7) ^ (rr & 7)) << 3;
    gll16(src + (long long)rr * ldg + cc, lds + (w * 16 + t * 8) * 64);
  }
}

// ---- prep: x -> [xh | xl] bf16, row-major [8192][2048] ------------------
__global__ __launch_bounds__(256) void prep_x(const float* __restrict__ x,
                                              unsigned short* __restrict__ A1) {
  const int idx4 = (blockIdx.x * 256 + threadIdx.x) * 4;
  const float4 xv = *reinterpret_cast<const float4*>(&x[idx4]);
  const int token = idx4 >> 10, c = idx4 & 1023;
  float vs[4] = {xv.x, xv.y, xv.z, xv.w};
  unsigned short hi[4], lo[4];
#pragma unroll
  for (int e = 0; e < 4; ++e) {
    unsigned short h = f2b(vs[e]);
    hi[e] = h;
    lo[e] = f2b(vs[e] - b2f(h));
  }
  uint2 hv, lv;
  hv.x = (unsigned int)hi[0] | ((unsigned int)hi[1] << 16);
  hv.y = (unsigned int)hi[2] | ((unsigned int)hi[3] << 16);
  lv.x = (unsigned int)lo[0] | ((unsigned int)lo[1] << 16);
  lv.y = (unsigned int)lo[2] | ((unsigned int)lo[3] << 16);
  *reinterpret_cast<uint2*>(&A1[token * 2048 + c]) = hv;
  *reinterpret_cast<uint2*>(&A1[token * 2048 + 1024 + c]) = lv;
}

// ---- concat biases into bcat[3584] --------------------------------------
__global__ void bias_cat(const float* __restrict__ bq, const float* __restrict__ bk,
                         const float* __restrict__ bv, const float* __restrict__ beq,
                         const float* __restrict__ bek, float* __restrict__ bcat) {
  const int n = blockIdx.x * 256 + threadIdx.x;
  if (n >= NCAT) return;
  float v;
  if (n < 1024) v = bq[n];
  else if (n < 2048) v = bk[n - 1024];
  else if (n < 3072) v = bv[n - 2048];
  else if (n < 3328) v = beq[n - 3072];
  else v = bek[n - 3328];
  bcat[n] = v;
}

// ---- transpose f32 weight [1024][C] -> bf16 dst[n][k] (B^T layout) ------
__global__ __launch_bounds__(256) void trans_w(const float* __restrict__ src, int C,
                                               unsigned short* __restrict__ dst, int dstld,
                                               int n_off, int dup) {
  __shared__ unsigned short t[64 * 68];
  const int k0 = blockIdx.x * 64, c0 = blockIdx.y * 64;
  const int tid = threadIdx.x;
#pragma unroll
  for (int i = 0; i < 16; ++i) {
    int e = i * 256 + tid;
    int r = e >> 6, c = e & 63;
    t[r * 68 + c] = f2b(src[(k0 + r) * C + c0 + c]);
  }
  __syncthreads();
#pragma unroll
  for (int i = 0; i < 16; ++i) {
    int e = i * 256 + tid;
    int r2 = e >> 6, c2 = e & 63;  // r2 = n index, c2 = k index
    unsigned short v = t[c2 * 68 + r2];
    dst[(n_off + c0 + r2) * dstld + k0 + c2] = v;
    if (dup) dst[(n_off + c0 + r2) * dstld + 1024 + k0 + c2] = v;
  }
}

// ---- transpose V columns of QKVEE -> Vt[hd_global][token] ---------------
__global__ __launch_bounds__(256) void trans_v(const unsigned short* __restrict__ QKVEE,
                                               unsigned short* __restrict__ Vt) {
  __shared__ unsigned short t[64 * 68];
  const int tok0 = blockIdx.x * 64, hc0 = blockIdx.y * 64;
  const int tid = threadIdx.x;
#pragma unroll
  for (int i = 0; i < 16; ++i) {
    int e = i * 256 + tid;
    int r = e >> 6, c = e & 63;  // r = token, c = hc
    t[r * 68 + c] = QKVEE[(long long)(tok0 + r) * NCAT + 2048 + hc0 + c];
  }
  __syncthreads();
#pragma unroll
  for (int i = 0; i < 16; ++i) {
    int e = i * 256 + tid;
    int r2 = e >> 6, c2 = e & 63;  // r2 = hc, c2 = token
    Vt[(long long)(hc0 + r2) * NTOK + tok0 + c2] = t[c2 * 68 + r2];
  }
}

// ---- 128x128 MFMA GEMM, global_load_lds staging (m97 structure) ---------
// A[M,K] bf16 row-major, Bt[N,K] bf16 row-major (B transposed)
// MODE 0: bf16 out = acc + bias[col]         (row-major)
// MODE 1: bf16 out^T = acc * scale           (TRANSPOSED write, 8B stores)
// MODE 2: f32  out = acc + bias[col]         (row-major)
template <int MODE>
__global__ __launch_bounds__(256) void gemm128(
    const unsigned short* __restrict__ A, long long sAz, int lda,
    const unsigned short* __restrict__ Bt, long long sBz, int ldb,
    void* __restrict__ Cv, long long sCz, int ldc,
    const float* __restrict__ bias, float scale, int K) {
  __shared__ __align__(16) unsigned short As[128 * 64];
  __shared__ __align__(16) unsigned short Bs[128 * 64];
  const int tid = threadIdx.x;
  const int lane = tid & 63, w = tid >> 6;
  const int wm = (w >> 1) * 64, wn = (w & 1) * 64;
  const int m0 = blockIdx.x * 128, n0 = blockIdx.y * 128;
  const int z = blockIdx.z;
  A += (long long)z * sAz;
  Bt += (long long)z * sBz;

  f32x4 acc[4][4];
#pragma unroll
  for (int i = 0; i < 4; ++i)
#pragma unroll
    for (int j = 0; j < 4; ++j)
#pragma unroll
      for (int e = 0; e < 4; ++e) acc[i][j][e] = 0.0f;

  const int srow = lane >> 3;          // 0..7
  const int scol = (lane & 7) << 3;    // 0..56

  for (int k0 = 0; k0 < K; k0 += 64) {
    // async stage: each wave stages 32 rows of A and of B (4x8 rows each)
#pragma unroll
    for (int t = 0; t < 4; ++t) {
      const int rr = w * 32 + t * 8 + srow;
      gll16(&A[(long long)(m0 + rr) * lda + k0 + scol], &As[(w * 32 + t * 8) * 64]);
      gll16(&Bt[(long long)(n0 + rr) * ldb + k0 + scol], &Bs[(w * 32 + t * 8) * 64]);
    }
    __syncthreads();  // drains vmcnt(0): tiles resident
#pragma unroll
    for (int kk = 0; kk < 2; ++kk) {
      const int ko = kk * 32 + (lane >> 4) * 8;
      short8 af[4], bf[4];
#pragma unroll
      for (int mf = 0; mf < 4; ++mf)
        af[mf] = *reinterpret_cast<const short8*>(&As[(wm + mf * 16 + (lane & 15)) * 64 + ko]);
#pragma unroll
      for (int nf = 0; nf < 4; ++nf)
        bf[nf] = *reinterpret_cast<const short8*>(&Bs[(wn + nf * 16 + (lane & 15)) * 64 + ko]);
#pragma unroll
      for (int mf = 0; mf < 4; ++mf)
#pragma unroll
        for (int nf = 0; nf < 4; ++nf)
          acc[mf][nf] = mfma_bf16(af[mf], bf[nf], acc[mf][nf]);
    }
    __syncthreads();  // all waves done reading before next overwrite
  }

  // C layout: col = lane&15, row = (lane>>4)*4 + j   [guide m89-verified]
  const int rb = m0 + wm + ((lane >> 4) << 2);
  const int cb = n0 + wn + (lane & 15);
#pragma unroll
  for (int mf = 0; mf < 4; ++mf) {
#pragma unroll
    for (int nf = 0; nf < 4; ++nf) {
      const int col = cb + nf * 16;
      const int row0 = rb + mf * 16;
      if (MODE == 1) {
        unsigned short* C = (unsigned short*)Cv + (long long)z * sCz;
        us4 pk;
#pragma unroll
        for (int j = 0; j < 4; ++j) pk[j] = f2b(acc[mf][nf][j] * scale);
        *reinterpret_cast<us4*>(&C[(long long)col * ldc + row0]) = pk;  // C^T, 8B store
      } else if (MODE == 0) {
        unsigned short* C = (unsigned short*)Cv + (long long)z * sCz;
        const float bc = bias[col];
#pragma unroll
        for (int j = 0; j < 4; ++j)
          C[(long long)(row0 + j) * ldc + col] = f2b(acc[mf][nf][j] + bc);
      } else {
        float* C = (float*)Cv + (long long)z * sCz;
        const float bc = bias[col];
#pragma unroll
        for (int j = 0; j < 4; ++j)
          C[(long long)(row0 + j) * ldc + col] = acc[mf][nf][j] + bc;
      }
    }
  }
}

// ---- fused flash attention with shared additive bias --------------------
// grid (32 q-tiles, 16 heads, 4 batch); 4 waves, each owns 16 q-rows.
// All LDS tiles XOR-swizzled (block ^= row&7) via pre-swizzled gll sources.
__global__ __launch_bounds__(256) void attn_kernel(
    const unsigned short* __restrict__ QKVEE,
    const unsigned short* __restrict__ Vt,
    const unsigned short* __restrict__ expT,   // [b][k][q] bf16
    const float* __restrict__ conf,
    unsigned short* __restrict__ ctx) {
  __shared__ __align__(16) unsigned short Qs[64 * 64];   // [q][d]
  __shared__ __align__(16) unsigned short Ks[64 * 64];   // [k][d]
  __shared__ __align__(16) unsigned short Vs[64 * 64];   // [d][tok]
  __shared__ __align__(16) unsigned short Bs[64 * 64];   // [k][q]
  __shared__ __align__(16) unsigned short Pl[4][16 * 64];// [q][k] per wave

  const int tid = threadIdx.x, lane = tid & 63, w = tid >> 6;
  const int qt = blockIdx.x, h = blockIdx.y, b = blockIdx.z;
  const int qbase = qt * 64;
  const long long tb = (long long)b * SS;
  const float cb2 = 0.3f * conf[b] * 1.44269504f;   // log2 domain
  const float SCL2 = 0.125f * 1.44269504f;

  stage64(QKVEE + (tb + qbase) * NCAT + h * HD, NCAT, Qs, w, lane);

  float m[4], l[4];
  f32x4 acc[4];
#pragma unroll
  for (int j = 0; j < 4; ++j) { m[j] = -3.0e38f; l[j] = 0.0f; }
#pragma unroll
  for (int nf = 0; nf < 4; ++nf)
#pragma unroll
    for (int j = 0; j < 4; ++j) acc[nf][j] = 0.0f;

  const int r0 = (lane >> 4) * 4;
  const int c0 = lane & 15;
  const int q0 = w * 16 + r0;

  for (int kb = 0; kb < SS; kb += 64) {
    stage64(QKVEE + (tb + kb) * NCAT + HIDDEN + h * HD, NCAT, Ks, w, lane);
    stage64(Vt + (long long)(h * HD) * NTOK + tb + kb, NTOK, Vs, w, lane);
    stage64(expT + (long long)b * SS * SS + (long long)kb * SS + qbase, SS, Bs, w, lane);
    __syncthreads();

    // S = Q K^T  (wave strip: [16 q][64 k])
    f32x4 s[4];
#pragma unroll
    for (int nf = 0; nf < 4; ++nf)
#pragma unroll
      for (int j = 0; j < 4; ++j) s[nf][j] = 0.0f;
#pragma unroll
    for (int kk = 0; kk < 2; ++kk) {
      const int bx = kk * 4 + (lane >> 4);
      short8 aq = lds16(Qs, w * 16 + (lane & 15), bx);
#pragma unroll
      for (int nf = 0; nf < 4; ++nf) {
        short8 bk = lds16(Ks, nf * 16 + (lane & 15), bx);
        s[nf] = mfma_bf16(aq, bk, s[nf]);
      }
    }

    // scale + shared bias (log2 domain); C layout: col=lane&15, row=(lane>>4)*4+j
    float sv[4][4];
#pragma unroll
    for (int nf = 0; nf < 4; ++nf) {
      const int key = nf * 16 + c0;
      const us4 bb = *reinterpret_cast<const us4*>(
          &Bs[key * 64 + (((q0 >> 3) ^ (key & 7)) << 3) + (q0 & 7)]);
#pragma unroll
      for (int j = 0; j < 4; ++j)
        sv[nf][j] = s[nf][j] * SCL2 + cb2 * b2f(bb[j]);
    }

    // row max across 64 keys
    float rmax[4];
#pragma unroll
    for (int j = 0; j < 4; ++j)
      rmax[j] = fmaxf(fmaxf(sv[0][j], sv[1][j]), fmaxf(sv[2][j], sv[3][j]));
#pragma unroll
    for (int mask = 1; mask <= 8; mask <<= 1)
#pragma unroll
      for (int j = 0; j < 4; ++j)
        rmax[j] = fmaxf(rmax[j], __shfl_xor(rmax[j], mask));

    // defer-max (T13): skip rescale unless max grew past threshold (log2: 8)
    int ok = 1;
#pragma unroll
    for (int j = 0; j < 4; ++j) ok &= (rmax[j] <= m[j] + 8.0f);
    if (!__all(ok)) {
#pragma unroll
      for (int j = 0; j < 4; ++j) {
        const float mn = fmaxf(m[j], rmax[j]);
        const float sc = __builtin_amdgcn_exp2f(m[j] - mn);
        m[j] = mn;
        l[j] *= sc;
#pragma unroll
        for (int nf = 0; nf < 4; ++nf) acc[nf][j] *= sc;
      }
    }

    float psum[4] = {0.f, 0.f, 0.f, 0.f};
#pragma unroll
    for (int nf = 0; nf < 4; ++nf) {
      const int key = nf * 16 + c0;
#pragma unroll
      for (int j = 0; j < 4; ++j) {
        const float p = __builtin_amdgcn_exp2f(sv[nf][j] - m[j]);
        psum[j] += p;
        const int row = r0 + j;
        Pl[w][row * 64 + (((key >> 3) ^ (row & 7)) << 3) + (key & 7)] = f2b(p);
      }
    }
#pragma unroll
    for (int mask = 1; mask <= 8; mask <<= 1)
#pragma unroll
      for (int j = 0; j < 4; ++j)
        psum[j] += __shfl_xor(psum[j], mask);
#pragma unroll
    for (int j = 0; j < 4; ++j) l[j] += psum[j];

    // PV: ctx[16 q][64 d] += P[16,64] @ V[64,64]
#pragma unroll
    for (int kk = 0; kk < 2; ++kk) {
      const int bx = kk * 4 + (lane >> 4);
      short8 ap = lds16(Pl[w], lane & 15, bx);
#pragma unroll
      for (int nf = 0; nf < 4; ++nf) {
        short8 bvv = lds16(Vs, nf * 16 + (lane & 15), bx);
        acc[nf] = mfma_bf16(ap, bvv, acc[nf]);
      }
    }
    __syncthreads();
  }

#pragma unroll
  for (int nf = 0; nf < 4; ++nf)
#pragma unroll
    for (int j = 0; j < 4; ++j) {
      const int qrow = qbase + w * 16 + r0 + j;
      const int d = nf * 16 + c0;
      ctx[(tb + qrow) * HIDDEN + h * HD + d] = f2b(acc[nf][j] / l[j]);
    }
}

extern "C" void kernel_launch(void* const* d_in, const int* in_sizes, int n_in,
                              void* d_out, int out_size, void* d_ws, size_t ws_size,
                              hipStream_t stream) {
  const float* x    = (const float*)d_in[0];
  const float* conf = (const float*)d_in[1];
  const float* Wq   = (const float*)d_in[2];
  const float* bq   = (const float*)d_in[3];
  const float* Wk   = (const float*)d_in[4];
  const float* bk   = (const float*)d_in[5];
  const float* Wv   = (const float*)d_in[6];
  const float* bv   = (const float*)d_in[7];
  const float* Weq  = (const float*)d_in[8];
  const float* beq  = (const float*)d_in[9];
  const float* Wek  = (const float*)d_in[10];
  const float* bek  = (const float*)d_in[11];
  const float* Wo   = (const float*)d_in[12];
  const float* bo   = (const float*)d_in[13];

  char* ws = (char*)d_ws;
  unsigned short* A1    = (unsigned short*)(ws);                               // 33,554,432 B
  unsigned short* WcatT = (unsigned short*)(ws + 33554432);                    // 14,680,064 B
  float*          bcat  = (float*)(ws + 48234496);                             //     16,384 B (padded)
  unsigned short* WoT   = (unsigned short*)(ws + 48250880);                    //  2,097,152 B
  unsigned short* QKVEE = (unsigned short*)(ws + 50348032);                    // 58,720,256 B
  unsigned short* Vt    = (unsigned short*)(ws + 109068288);                   // 16,777,216 B
  unsigned short* ctx   = (unsigned short*)(ws + 125845504);                   // 16,777,216 B
  // exp-scores transposed [b][k][q] (bf16, 33,554,432 B) lives in d_out;
  // overwritten by the final GEMM.
  unsigned short* expT  = (unsigned short*)d_out;

  prep_x<<<dim3(8192), dim3(256), 0, stream>>>(x, A1);
  bias_cat<<<dim3(14), dim3(256), 0, stream>>>(bq, bk, bv, beq, bek, bcat);
  trans_w<<<dim3(16, 16), dim3(256), 0, stream>>>(Wq, 1024, WcatT, 2048, 0, 1);
  trans_w<<<dim3(16, 16), dim3(256), 0, stream>>>(Wk, 1024, WcatT, 2048, 1024, 1);
  trans_w<<<dim3(16, 16), dim3(256), 0, stream>>>(Wv, 1024, WcatT, 2048, 2048, 1);
  trans_w<<<dim3(16, 4),  dim3(256), 0, stream>>>(Weq, 256, WcatT, 2048, 3072, 1);
  trans_w<<<dim3(16, 4),  dim3(256), 0, stream>>>(Wek, 256, WcatT, 2048, 3328, 1);
  trans_w<<<dim3(16, 16), dim3(256), 0, stream>>>(Wo, 1024, WoT, 1024, 0, 0);

  // Q|K|V|EQ|EK = [xh|xl] @ [W;W] + bias  (2-term fp32-emulation via bf16 MFMA)
  gemm128<0><<<dim3(64, 28), dim3(256), 0, stream>>>(
      A1, 0, 2048, WcatT, 0, 2048, QKVEE, 0, NCAT, bcat, 1.0f, 2048);

  trans_v<<<dim3(128, 16), dim3(256), 0, stream>>>(QKVEE, Vt);

  // expT[b][k][q] = ((EQ @ EK^T)/16)^T  -> bf16 in d_out (transposed write)
  gemm128<1><<<dim3(16, 16, 4), dim3(256), 0, stream>>>(
      QKVEE + 3072, (long long)SS * NCAT, NCAT,
      QKVEE + 3328, (long long)SS * NCAT, NCAT,
      expT, (long long)SS * SS, SS, nullptr, 1.0f / 16.0f, 256);

  attn_kernel<<<dim3(32, 16, 4), dim3(256), 0, stream>>>(QKVEE, Vt, expT, conf, ctx);

  // out = ctx @ Wo + bo  (fp32 out, overwrites exp-scores scratch)
  gemm128<2><<<dim3(64, 8), dim3(256), 0, stream>>>(
      ctx, 0, 1024, WoT, 0, 1024, d_out, 0, 1024, bo, 1.0f, 1024);
}

// Round 4
// 535.848 us; speedup vs baseline: 1.2845x; 1.1599x over previous
//
#include <hip/hip_runtime.h>

#define HIDDEN 1024
#define EXPD   256
#define NH     16
#define HD     64
#define BB     4
#define SS     2048
#define NTOK   (BB*SS)   /* 8192 */
#define NCAT   3584      /* 3*1024 + 2*256 */
#define QSCALE 0.18033688f  /* 0.125 * log2(e): folded into Wq/bq */

typedef __attribute__((ext_vector_type(8))) short short8;
typedef __attribute__((ext_vector_type(4))) float f32x4;
typedef __attribute__((ext_vector_type(4))) unsigned short us4;

__device__ __forceinline__ unsigned short f2b(float f) {
  unsigned int u = __float_as_uint(f);
  u += 0x7fffu + ((u >> 16) & 1u);
  return (unsigned short)(u >> 16);
}
__device__ __forceinline__ float b2f(unsigned short u) {
  return __uint_as_float(((unsigned int)u) << 16);
}
__device__ __forceinline__ f32x4 mfma_bf16(short8 a, short8 b, f32x4 c) {
  return __builtin_amdgcn_mfma_f32_16x16x32_bf16(a, b, c, 0, 0, 0);
}
// packed f32x2 -> bf16x2 (RNE), low half = first arg
__device__ __forceinline__ unsigned int cvt_pk(float lo, float hi) {
  unsigned int r;
  asm("v_cvt_pk_bf16_f32 %0, %1, %2" : "=v"(r) : "v"(lo), "v"(hi));
  return r;
}

// async global->LDS, 16B per lane. LDS dest: wave-uniform base + lane*16.
__device__ __forceinline__ void gll16(const unsigned short* g, unsigned short* l) {
  __builtin_amdgcn_global_load_lds(
      (const __attribute__((address_space(1))) void*)g,
      (__attribute__((address_space(3))) void*)l, 16, 0, 0);
}

// swizzled 16B LDS read: logical (row, 16B-block bx) of a [*][64]-short tile
__device__ __forceinline__ short8 lds16(const unsigned short* base, int row, int bx) {
  return *reinterpret_cast<const short8*>(base + row * 64 + ((bx ^ (row & 7)) << 3));
}

// stage a 64x64-short tile from row-major global into swizzled LDS.
// storage slot (lane&7) of row r holds logical block (lane&7)^(r&7)  [m173 pattern]
__device__ __forceinline__ void stage64(const unsigned short* __restrict__ src,
                                        long long ldg, unsigned short* lds,
                                        int w, int lane) {
#pragma unroll
  for (int t = 0; t < 2; ++t) {
    const int rr = w * 16 + t * 8 + (lane >> 3);
    const int cc = ((lane & 7) ^ (rr & 7)) << 3;
    gll16(src + (long long)rr * ldg + cc, lds + (w * 16 + t * 8) * 64);
  }
}

// ---- prep: x -> [xh | xl] bf16, row-major [8192][2048] ------------------
__global__ __launch_bounds__(256) void prep_x(const float* __restrict__ x,
                                              unsigned short* __restrict__ A1) {
  const int idx4 = (blockIdx.x * 256 + threadIdx.x) * 4;
  const float4 xv = *reinterpret_cast<const float4*>(&x[idx4]);
  const int token = idx4 >> 10, c = idx4 & 1023;
  float vs[4] = {xv.x, xv.y, xv.z, xv.w};
  unsigned short hi[4], lo[4];
#pragma unroll
  for (int e = 0; e < 4; ++e) {
    unsigned short h = f2b(vs[e]);
    hi[e] = h;
    lo[e] = f2b(vs[e] - b2f(h));
  }
  uint2 hv, lv;
  hv.x = (unsigned int)hi[0] | ((unsigned int)hi[1] << 16);
  hv.y = (unsigned int)hi[2] | ((unsigned int)hi[3] << 16);
  lv.x = (unsigned int)lo[0] | ((unsigned int)lo[1] << 16);
  lv.y = (unsigned int)lo[2] | ((unsigned int)lo[3] << 16);
  *reinterpret_cast<uint2*>(&A1[token * 2048 + c]) = hv;
  *reinterpret_cast<uint2*>(&A1[token * 2048 + 1024 + c]) = lv;
}

// ---- concat biases into bcat[3584]; bq pre-scaled for log2-domain attn --
__global__ void bias_cat(const float* __restrict__ bq, const float* __restrict__ bk,
                         const float* __restrict__ bv, const float* __restrict__ beq,
                         const float* __restrict__ bek, float* __restrict__ bcat) {
  const int n = blockIdx.x * 256 + threadIdx.x;
  if (n >= NCAT) return;
  float v;
  if (n < 1024) v = bq[n] * QSCALE;
  else if (n < 2048) v = bk[n - 1024];
  else if (n < 3072) v = bv[n - 2048];
  else if (n < 3328) v = beq[n - 3072];
  else v = bek[n - 3328];
  bcat[n] = v;
}

// ---- transpose f32 weight [1024][C] -> bf16 dst[n][k] (B^T layout) ------
__global__ __launch_bounds__(256) void trans_w(const float* __restrict__ src, int C,
                                               unsigned short* __restrict__ dst, int dstld,
                                               int n_off, int dup, float wscale) {
  __shared__ unsigned short t[64 * 68];
  const int k0 = blockIdx.x * 64, c0 = blockIdx.y * 64;
  const int tid = threadIdx.x;
#pragma unroll
  for (int i = 0; i < 16; ++i) {
    int e = i * 256 + tid;
    int r = e >> 6, c = e & 63;
    t[r * 68 + c] = f2b(src[(k0 + r) * C + c0 + c] * wscale);
  }
  __syncthreads();
#pragma unroll
  for (int i = 0; i < 16; ++i) {
    int e = i * 256 + tid;
    int r2 = e >> 6, c2 = e & 63;  // r2 = n index, c2 = k index
    unsigned short v = t[c2 * 68 + r2];
    dst[(n_off + c0 + r2) * dstld + k0 + c2] = v;
    if (dup) dst[(n_off + c0 + r2) * dstld + 1024 + k0 + c2] = v;
  }
}

// ---- transpose V columns of QKVEE -> Vt[hd_global][token] ---------------
__global__ __launch_bounds__(256) void trans_v(const unsigned short* __restrict__ QKVEE,
                                               unsigned short* __restrict__ Vt) {
  __shared__ unsigned short t[64 * 68];
  const int tok0 = blockIdx.x * 64, hc0 = blockIdx.y * 64;
  const int tid = threadIdx.x;
#pragma unroll
  for (int i = 0; i < 16; ++i) {
    int e = i * 256 + tid;
    int r = e >> 6, c = e & 63;  // r = token, c = hc
    t[r * 68 + c] = QKVEE[(long long)(tok0 + r) * NCAT + 2048 + hc0 + c];
  }
  __syncthreads();
#pragma unroll
  for (int i = 0; i < 16; ++i) {
    int e = i * 256 + tid;
    int r2 = e >> 6, c2 = e & 63;  // r2 = hc, c2 = token
    Vt[(long long)(hc0 + r2) * NTOK + tok0 + c2] = t[c2 * 68 + r2];
  }
}

// ---- 128x128 MFMA GEMM, global_load_lds staging (m97 structure) ---------
// A[M,K] bf16 row-major, Bt[N,K] bf16 row-major (B transposed)
// MODE 0: bf16 out = acc + bias[col]               (row-major)
// MODE 1: bf16 out^T = acc * scale * cmul[z]       (TRANSPOSED write)
// MODE 2: f32  out = acc + bias[col]               (row-major)
// XCD-aware bijective block swizzle (requires gridDim.x*gridDim.y % 8 == 0)
template <int MODE>
__global__ __launch_bounds__(256) void gemm128(
    const unsigned short* __restrict__ A, long long sAz, int lda,
    const unsigned short* __restrict__ Bt, long long sBz, int ldb,
    void* __restrict__ Cv, long long sCz, int ldc,
    const float* __restrict__ bias, const float* __restrict__ cmul,
    float scale, int K) {
  __shared__ __align__(16) unsigned short As[128 * 64];
  __shared__ __align__(16) unsigned short Bs[128 * 64];
  const int tid = threadIdx.x;
  const int lane = tid & 63, w = tid >> 6;
  const int wm = (w >> 1) * 64, wn = (w & 1) * 64;
  // XCD swizzle (m204 bijective form; nwg%8==0 for all our launches)
  int flat = blockIdx.y * gridDim.x + blockIdx.x;
  const int nwg = gridDim.x * gridDim.y;
  flat = (flat & 7) * (nwg >> 3) + (flat >> 3);
  const int m0 = (flat % gridDim.x) * 128, n0 = (flat / gridDim.x) * 128;
  const int z = blockIdx.z;
  A += (long long)z * sAz;
  Bt += (long long)z * sBz;

  f32x4 acc[4][4];
#pragma unroll
  for (int i = 0; i < 4; ++i)
#pragma unroll
    for (int j = 0; j < 4; ++j)
#pragma unroll
      for (int e = 0; e < 4; ++e) acc[i][j][e] = 0.0f;

  const int srow = lane >> 3;          // 0..7
  const int scol = (lane & 7) << 3;    // 0..56

  for (int k0 = 0; k0 < K; k0 += 64) {
    // async stage: each wave stages 32 rows of A and of B (4x8 rows each)
#pragma unroll
    for (int t = 0; t < 4; ++t) {
      const int rr = w * 32 + t * 8 + srow;
      gll16(&A[(long long)(m0 + rr) * lda + k0 + scol], &As[(w * 32 + t * 8) * 64]);
      gll16(&Bt[(long long)(n0 + rr) * ldb + k0 + scol], &Bs[(w * 32 + t * 8) * 64]);
    }
    __syncthreads();  // drains vmcnt(0): tiles resident
#pragma unroll
    for (int kk = 0; kk < 2; ++kk) {
      const int ko = kk * 32 + (lane >> 4) * 8;
      short8 af[4], bf[4];
#pragma unroll
      for (int mf = 0; mf < 4; ++mf)
        af[mf] = *reinterpret_cast<const short8*>(&As[(wm + mf * 16 + (lane & 15)) * 64 + ko]);
#pragma unroll
      for (int nf = 0; nf < 4; ++nf)
        bf[nf] = *reinterpret_cast<const short8*>(&Bs[(wn + nf * 16 + (lane & 15)) * 64 + ko]);
#pragma unroll
      for (int mf = 0; mf < 4; ++mf)
#pragma unroll
        for (int nf = 0; nf < 4; ++nf)
          acc[mf][nf] = mfma_bf16(af[mf], bf[nf], acc[mf][nf]);
    }
    __syncthreads();  // all waves done reading before next overwrite
  }

  // C layout: col = lane&15, row = (lane>>4)*4 + j   [guide m89-verified]
  const int rb = m0 + wm + ((lane >> 4) << 2);
  const int cb = n0 + wn + (lane & 15);
  float scl = scale;
  if (MODE == 1) scl *= cmul[z];
#pragma unroll
  for (int mf = 0; mf < 4; ++mf) {
#pragma unroll
    for (int nf = 0; nf < 4; ++nf) {
      const int col = cb + nf * 16;
      const int row0 = rb + mf * 16;
      if (MODE == 1) {
        unsigned short* C = (unsigned short*)Cv + (long long)z * sCz;
        us4 pk;
#pragma unroll
        for (int j = 0; j < 4; ++j) pk[j] = f2b(acc[mf][nf][j] * scl);
        *reinterpret_cast<us4*>(&C[(long long)col * ldc + row0]) = pk;  // C^T, 8B store
      } else if (MODE == 0) {
        unsigned short* C = (unsigned short*)Cv + (long long)z * sCz;
        const float bc = bias[col];
#pragma unroll
        for (int j = 0; j < 4; ++j)
          C[(long long)(row0 + j) * ldc + col] = f2b(acc[mf][nf][j] + bc);
      } else {
        float* C = (float*)Cv + (long long)z * sCz;
        const float bc = bias[col];
#pragma unroll
        for (int j = 0; j < 4; ++j)
          C[(long long)(row0 + j) * ldc + col] = acc[mf][nf][j] + bc;
      }
    }
  }
}

// ---- fused flash attention, S^T form, P fully in registers --------------
// 1-D grid 2048: xcd = flat&7 carries qt&7; within-XCD order: h fastest,
// so the 16 h-blocks sharing one expS slice co-reside on one XCD's L2.
// Lane view after S^T = K·Q^T: lane (g=lane>>4, c0=lane&15) holds
// S^T[k = nf*16 + g*4 + j][q = w*16 + c0]. PV uses a k-axis permutation
// κ(kk,g,t) = (2kk+(t>>2))*16 + g*4 + (t&3) applied to BOTH operands:
// P-fragments come straight from local cvt_pk words; V is read from LDS
// at the κ-matched token columns. No cross-lane data movement for P.
__global__ __launch_bounds__(256, 4) void attn_kernel(
    const unsigned short* __restrict__ QKVEE,
    const unsigned short* __restrict__ Vt,
    const unsigned short* __restrict__ expS,   // [b][q][k] bf16, pre-scaled
    unsigned short* __restrict__ ctx) {
  __shared__ __align__(16) unsigned short Ks[64 * 64];   // [k][d]
  __shared__ __align__(16) unsigned short Vs[64 * 64];   // [d][tok]
  __shared__ __align__(16) unsigned short Bs[64 * 64];   // [q][k]

  const int tid = threadIdx.x, lane = tid & 63, w = tid >> 6;
  const int flat = blockIdx.x;
  const int pos = flat >> 3;
  const int h = pos & 15, b = (pos >> 4) & 3;
  const int qt = (flat & 7) + 8 * (pos >> 6);
  const int qbase = qt * 64;
  const long long tb = (long long)b * SS;

  const int c0 = lane & 15, g = lane >> 4, r0 = g * 4;
  const int qr = w * 16 + c0;   // this lane's query row within the 64-q tile

  // Q fragments in registers (Q pre-scaled by 0.125*log2e via Wq/bq)
  short8 qf[2];
#pragma unroll
  for (int kk = 0; kk < 2; ++kk)
    qf[kk] = *reinterpret_cast<const short8*>(
        &QKVEE[(tb + qbase + qr) * NCAT + h * HD + kk * 32 + g * 8]);

  float m = -3.0e38f, l = 0.0f;
  f32x4 acc[4];
#pragma unroll
  for (int nf = 0; nf < 4; ++nf)
#pragma unroll
    for (int j = 0; j < 4; ++j) acc[nf][j] = 0.0f;

  for (int kb = 0; kb < SS; kb += 64) {
    stage64(QKVEE + (tb + kb) * NCAT + HIDDEN + h * HD, NCAT, Ks, w, lane);
    stage64(Vt + (long long)(h * HD) * NTOK + tb + kb, NTOK, Vs, w, lane);
    stage64(expS + (tb + qbase) * SS + kb, SS, Bs, w, lane);
    __syncthreads();

    // S^T = K·Q^T
    f32x4 s[4];
#pragma unroll
    for (int nf = 0; nf < 4; ++nf)
#pragma unroll
      for (int j = 0; j < 4; ++j) s[nf][j] = 0.0f;
#pragma unroll
    for (int kk = 0; kk < 2; ++kk) {
      const int bx = kk * 4 + g;
#pragma unroll
      for (int nf = 0; nf < 4; ++nf) {
        short8 kf = lds16(Ks, nf * 16 + c0, bx);
        s[nf] = mfma_bf16(kf, qf[kk], s[nf]);
      }
    }

    // add shared bias (log2 domain, conf-weighted); row = THIS lane's q (qr)
    float sv[4][4];
#pragma unroll
    for (int nf = 0; nf < 4; ++nf) {
      const int col = nf * 16 + r0;
      const us4 bb = *reinterpret_cast<const us4*>(
          &Bs[qr * 64 + (((col >> 3) ^ (qr & 7)) << 3) + (col & 7)]);
#pragma unroll
      for (int j = 0; j < 4; ++j) sv[nf][j] = s[nf][j] + b2f(bb[j]);
    }

    // row-max for q=qr: in-lane tree (16) + 2 shuffles across g-groups
    float t0 = fmaxf(fmaxf(sv[0][0], sv[0][1]), fmaxf(sv[0][2], sv[0][3]));
    float t1 = fmaxf(fmaxf(sv[1][0], sv[1][1]), fmaxf(sv[1][2], sv[1][3]));
    float t2 = fmaxf(fmaxf(sv[2][0], sv[2][1]), fmaxf(sv[2][2], sv[2][3]));
    float t3 = fmaxf(fmaxf(sv[3][0], sv[3][1]), fmaxf(sv[3][2], sv[3][3]));
    float rmax = fmaxf(fmaxf(t0, t1), fmaxf(t2, t3));
    rmax = fmaxf(rmax, __shfl_xor(rmax, 16));
    rmax = fmaxf(rmax, __shfl_xor(rmax, 32));

    // defer-max (T13): rescale only when max grew past 8 (log2 units)
    if (__any(rmax > m + 8.0f)) {
      const float mn = fmaxf(m, rmax);
      const float sc = __builtin_amdgcn_exp2f(m - mn);
      m = mn;
      l *= sc;
      float scj[4];
#pragma unroll
      for (int j = 0; j < 4; ++j) scj[j] = __shfl(sc, r0 + j);
#pragma unroll
      for (int nf = 0; nf < 4; ++nf)
#pragma unroll
        for (int j = 0; j < 4; ++j) acc[nf][j] *= scj[j];
    }

    // P = exp2(sv - m), packed to bf16 pairs entirely in-lane
    unsigned int wds[4][2];
    float ps0 = 0.f, ps1 = 0.f;
#pragma unroll
    for (int nf = 0; nf < 4; ++nf) {
      const float p0 = __builtin_amdgcn_exp2f(sv[nf][0] - m);
      const float p1 = __builtin_amdgcn_exp2f(sv[nf][1] - m);
      const float p2 = __builtin_amdgcn_exp2f(sv[nf][2] - m);
      const float p3 = __builtin_amdgcn_exp2f(sv[nf][3] - m);
      wds[nf][0] = cvt_pk(p0, p1);
      wds[nf][1] = cvt_pk(p2, p3);
      ps0 += p0 + p1;
      ps1 += p2 + p3;
    }
    float psum = ps0 + ps1;
    psum += __shfl_xor(psum, 16);
    psum += __shfl_xor(psum, 32);
    l += psum;

    // PV over κ-permuted token axis: A from local words, V at κ columns
#pragma unroll
    for (int kk = 0; kk < 2; ++kk) {
      union { unsigned int u[4]; short8 v8; } pa;
      pa.u[0] = wds[2 * kk][0];
      pa.u[1] = wds[2 * kk][1];
      pa.u[2] = wds[2 * kk + 1][0];
      pa.u[3] = wds[2 * kk + 1][1];
#pragma unroll
      for (int nf = 0; nf < 4; ++nf) {
        const int rowd = nf * 16 + c0;
        const int cA = kk * 32 + r0;
        const int cB = cA + 16;
        union { us4 h2[2]; short8 v8; } vf;
        vf.h2[0] = *reinterpret_cast<const us4*>(
            &Vs[rowd * 64 + (((cA >> 3) ^ (rowd & 7)) << 3) + (cA & 7)]);
        vf.h2[1] = *reinterpret_cast<const us4*>(
            &Vs[rowd * 64 + (((cB >> 3) ^ (rowd & 7)) << 3) + (cB & 7)]);
        acc[nf] = mfma_bf16(pa.v8, vf.v8, acc[nf]);
      }
    }
    __syncthreads();
  }

  float linv[4];
#pragma unroll
  for (int j = 0; j < 4; ++j) linv[j] = 1.0f / __shfl(l, r0 + j);
#pragma unroll
  for (int nf = 0; nf < 4; ++nf)
#pragma unroll
    for (int j = 0; j < 4; ++j) {
      const int qrow = qbase + w * 16 + r0 + j;
      const int d = nf * 16 + c0;
      ctx[(tb + qrow) * HIDDEN + h * HD + d] = f2b(acc[nf][j] * linv[j]);
    }
}

extern "C" void kernel_launch(void* const* d_in, const int* in_sizes, int n_in,
                              void* d_out, int out_size, void* d_ws, size_t ws_size,
                              hipStream_t stream) {
  const float* x    = (const float*)d_in[0];
  const float* conf = (const float*)d_in[1];
  const float* Wq   = (const float*)d_in[2];
  const float* bq   = (const float*)d_in[3];
  const float* Wk   = (const float*)d_in[4];
  const float* bk   = (const float*)d_in[5];
  const float* Wv   = (const float*)d_in[6];
  const float* bv   = (const float*)d_in[7];
  const float* Weq  = (const float*)d_in[8];
  const float* beq  = (const float*)d_in[9];
  const float* Wek  = (const float*)d_in[10];
  const float* bek  = (const float*)d_in[11];
  const float* Wo   = (const float*)d_in[12];
  const float* bo   = (const float*)d_in[13];

  char* ws = (char*)d_ws;
  unsigned short* A1    = (unsigned short*)(ws);                               // 33,554,432 B
  unsigned short* WcatT = (unsigned short*)(ws + 33554432);                    // 14,680,064 B
  float*          bcat  = (float*)(ws + 48234496);                             //     16,384 B (padded)
  unsigned short* WoT   = (unsigned short*)(ws + 48250880);                    //  2,097,152 B
  unsigned short* QKVEE = (unsigned short*)(ws + 50348032);                    // 58,720,256 B
  unsigned short* Vt    = (unsigned short*)(ws + 109068288);                   // 16,777,216 B
  unsigned short* ctx   = (unsigned short*)(ws + 125845504);                   // 16,777,216 B
  // exp-scores [b][q][k] (bf16, 33,554,432 B) lives in d_out; overwritten
  // by the final GEMM after attention consumes it.
  unsigned short* expS  = (unsigned short*)d_out;

  prep_x<<<dim3(8192), dim3(256), 0, stream>>>(x, A1);
  bias_cat<<<dim3(14), dim3(256), 0, stream>>>(bq, bk, bv, beq, bek, bcat);
  trans_w<<<dim3(16, 16), dim3(256), 0, stream>>>(Wq, 1024, WcatT, 2048, 0, 1, QSCALE);
  trans_w<<<dim3(16, 16), dim3(256), 0, stream>>>(Wk, 1024, WcatT, 2048, 1024, 1, 1.0f);
  trans_w<<<dim3(16, 16), dim3(256), 0, stream>>>(Wv, 1024, WcatT, 2048, 2048, 1, 1.0f);
  trans_w<<<dim3(16, 4),  dim3(256), 0, stream>>>(Weq, 256, WcatT, 2048, 3072, 1, 1.0f);
  trans_w<<<dim3(16, 4),  dim3(256), 0, stream>>>(Wek, 256, WcatT, 2048, 3328, 1, 1.0f);
  trans_w<<<dim3(16, 16), dim3(256), 0, stream>>>(Wo, 1024, WoT, 1024, 0, 0, 1.0f);

  // Q|K|V|EQ|EK = [xh|xl] @ [W;W] + bias  (2-term fp32-emulation via bf16 MFMA)
  gemm128<0><<<dim3(64, 28), dim3(256), 0, stream>>>(
      A1, 0, 2048, WcatT, 0, 2048, QKVEE, 0, NCAT, bcat, nullptr, 1.0f, 2048);

  trans_v<<<dim3(128, 16), dim3(256), 0, stream>>>(QKVEE, Vt);

  // expS[b][q][k] = ((EQ·EK^T)/16 * 0.3*conf[b]*log2e)  via C=EK·EQ^T + C^T write
  gemm128<1><<<dim3(16, 16, 4), dim3(256), 0, stream>>>(
      QKVEE + 3328, (long long)SS * NCAT, NCAT,
      QKVEE + 3072, (long long)SS * NCAT, NCAT,
      expS, (long long)SS * SS, SS, nullptr, conf,
      0.3f * 1.44269504f / 16.0f, 256);

  attn_kernel<<<dim3(2048), dim3(256), 0, stream>>>(QKVEE, Vt, expS, ctx);

  // out = ctx @ Wo + bo  (fp32 out, overwrites exp-scores scratch)
  gemm128<2><<<dim3(64, 8), dim3(256), 0, stream>>>(
      ctx, 0, 1024, WoT, 0, 1024, d_out, 0, 1024, bo, nullptr, 1.0f, 1024);
}

// Round 6
// 476.398 us; speedup vs baseline: 1.4448x; 1.1248x over previous
//
#include <hip/hip_runtime.h>

#define HIDDEN 1024
#define EXPD   256
#define NH     16
#define HD     64
#define BB     4
#define SS     2048
#define NTOK   (BB*SS)   /* 8192 */
#define NCAT   3584      /* 3*1024 + 2*256 */
#define QSCALE 0.18033688f  /* 0.125 * log2(e): folded into Wq/bq */

typedef __attribute__((ext_vector_type(8))) short short8;
typedef __attribute__((ext_vector_type(4))) float f32x4;
typedef __attribute__((ext_vector_type(4))) unsigned short us4;

__device__ __forceinline__ unsigned short f2b(float f) {
  unsigned int u = __float_as_uint(f);
  u += 0x7fffu + ((u >> 16) & 1u);
  return (unsigned short)(u >> 16);
}
__device__ __forceinline__ float b2f(unsigned short u) {
  return __uint_as_float(((unsigned int)u) << 16);
}
__device__ __forceinline__ f32x4 mfma_bf16(short8 a, short8 b, f32x4 c) {
  return __builtin_amdgcn_mfma_f32_16x16x32_bf16(a, b, c, 0, 0, 0);
}
// packed f32x2 -> bf16x2 (RNE), low half = first arg
__device__ __forceinline__ unsigned int cvt_pk(float lo, float hi) {
  unsigned int r;
  asm("v_cvt_pk_bf16_f32 %0, %1, %2" : "=v"(r) : "v"(lo), "v"(hi));
  return r;
}

// async global->LDS, 16B per lane. LDS dest: wave-uniform base + lane*16.
__device__ __forceinline__ void gll16(const unsigned short* g, unsigned short* l) {
  __builtin_amdgcn_global_load_lds(
      (const __attribute__((address_space(1))) void*)g,
      (__attribute__((address_space(3))) void*)l, 16, 0, 0);
}

// swizzled 16B LDS read: logical (row, 16B-block bx) of a [*][64]-short tile
__device__ __forceinline__ short8 lds16(const unsigned short* base, int row, int bx) {
  return *reinterpret_cast<const short8*>(base + row * 64 + ((bx ^ (row & 7)) << 3));
}

// stage a 64x64-short tile from row-major global into swizzled LDS (256 thr).
__device__ __forceinline__ void stage64(const unsigned short* __restrict__ src,
                                        long long ldg, unsigned short* lds,
                                        int w, int lane) {
#pragma unroll
  for (int t = 0; t < 2; ++t) {
    const int rr = w * 16 + t * 8 + (lane >> 3);
    const int cc = ((lane & 7) ^ (rr & 7)) << 3;
    gll16(src + (long long)rr * ldg + cc, lds + (w * 16 + t * 8) * 64);
  }
}

// one gll call for 512-thread blocks: 64 rows x 64 shorts (8 KB), swizzled src
__device__ __forceinline__ void g2l_call(const unsigned short* __restrict__ g,
                                         long long ldg, unsigned short* lds, int tid) {
  const int r = tid >> 3;
  const int c = ((tid & 7) ^ (r & 7)) << 3;
  gll16(g + (long long)r * ldg + c, lds + (tid >> 6) * 512);
}

// ---- prep: x -> [xh | xl] bf16, row-major [8192][2048] ------------------
__global__ __launch_bounds__(256) void prep_x(const float* __restrict__ x,
                                              unsigned short* __restrict__ A1) {
  const int idx4 = (blockIdx.x * 256 + threadIdx.x) * 4;
  const float4 xv = *reinterpret_cast<const float4*>(&x[idx4]);
  const int token = idx4 >> 10, c = idx4 & 1023;
  float vs[4] = {xv.x, xv.y, xv.z, xv.w};
  unsigned short hi[4], lo[4];
#pragma unroll
  for (int e = 0; e < 4; ++e) {
    unsigned short h = f2b(vs[e]);
    hi[e] = h;
    lo[e] = f2b(vs[e] - b2f(h));
  }
  uint2 hv, lv;
  hv.x = (unsigned int)hi[0] | ((unsigned int)hi[1] << 16);
  hv.y = (unsigned int)hi[2] | ((unsigned int)hi[3] << 16);
  lv.x = (unsigned int)lo[0] | ((unsigned int)lo[1] << 16);
  lv.y = (unsigned int)lo[2] | ((unsigned int)lo[3] << 16);
  *reinterpret_cast<uint2*>(&A1[token * 2048 + c]) = hv;
  *reinterpret_cast<uint2*>(&A1[token * 2048 + 1024 + c]) = lv;
}

// ---- concat biases into bcat[3584]; bq pre-scaled for log2-domain attn --
__global__ void bias_cat(const float* __restrict__ bq, const float* __restrict__ bk,
                         const float* __restrict__ bv, const float* __restrict__ beq,
                         const float* __restrict__ bek, float* __restrict__ bcat) {
  const int n = blockIdx.x * 256 + threadIdx.x;
  if (n >= NCAT) return;
  float v;
  if (n < 1024) v = bq[n] * QSCALE;
  else if (n < 2048) v = bk[n - 1024];
  else if (n < 3072) v = bv[n - 2048];
  else if (n < 3328) v = beq[n - 3072];
  else v = bek[n - 3328];
  bcat[n] = v;
}

// ---- transpose f32 weight [1024][C] -> bf16 dst[n][k] (B^T layout) ------
__global__ __launch_bounds__(256) void trans_w(const float* __restrict__ src, int C,
                                               unsigned short* __restrict__ dst, int dstld,
                                               int n_off, int dup, float wscale) {
  __shared__ unsigned short t[64 * 68];
  const int k0 = blockIdx.x * 64, c0 = blockIdx.y * 64;
  const int tid = threadIdx.x;
#pragma unroll
  for (int i = 0; i < 16; ++i) {
    int e = i * 256 + tid;
    int r = e >> 6, c = e & 63;
    t[r * 68 + c] = f2b(src[(k0 + r) * C + c0 + c] * wscale);
  }
  __syncthreads();
#pragma unroll
  for (int i = 0; i < 16; ++i) {
    int e = i * 256 + tid;
    int r2 = e >> 6, c2 = e & 63;  // r2 = n index, c2 = k index
    unsigned short v = t[c2 * 68 + r2];
    dst[(n_off + c0 + r2) * dstld + k0 + c2] = v;
    if (dup) dst[(n_off + c0 + r2) * dstld + 1024 + k0 + c2] = v;
  }
}

// ---- transpose V columns of QKVEE -> Vt[hd_global][token] ---------------
__global__ __launch_bounds__(256) void trans_v(const unsigned short* __restrict__ QKVEE,
                                               unsigned short* __restrict__ Vt) {
  __shared__ unsigned short t[64 * 68];
  const int tok0 = blockIdx.x * 64, hc0 = blockIdx.y * 64;
  const int tid = threadIdx.x;
#pragma unroll
  for (int i = 0; i < 16; ++i) {
    int e = i * 256 + tid;
    int r = e >> 6, c = e & 63;  // r = token, c = hc
    t[r * 68 + c] = QKVEE[(long long)(tok0 + r) * NCAT + 2048 + hc0 + c];
  }
  __syncthreads();
#pragma unroll
  for (int i = 0; i < 16; ++i) {
    int e = i * 256 + tid;
    int r2 = e >> 6, c2 = e & 63;  // r2 = hc, c2 = token
    Vt[(long long)(hc0 + r2) * NTOK + tok0 + c2] = t[c2 * 68 + r2];
  }
}

// ---- deep-pipelined 256x128 GEMM, ring-3 LDS, counted vmcnt -------------
// A[M,K] bf16 rm, Bt[N,K] bf16 rm. BK=64. 512 thr = 8 waves (4M x 2N),
// per-wave output 64x64. LDS: 3 K-tile ring (144 KB) -> while computing
// tile t (buf t%3), tile t+1 is landed in buf (t+1)%3 and tile t+2 streams
// into buf (t+2)%3 (6 gll16 in flight; vmcnt(6) + raw s_barrier per tile
// guarantees t+1 landed, never drains to 0 in-loop). T2 XOR swizzle on all
// LDS reads; T5 setprio around MFMA clusters. Tail iters issue harmless
// wrapped dummy stages so vmcnt counts stay uniform.
// MODE 0: bf16 out = acc + bias[col];  MODE 2: f32 out = acc + bias[col]
template <int MODE>
__global__ __launch_bounds__(512, 2) void gemm256(
    const unsigned short* __restrict__ A, int lda,
    const unsigned short* __restrict__ Bt, int ldb,
    void* __restrict__ Cv, int ldc,
    const float* __restrict__ bias, int K, int nbn) {
  __shared__ __align__(16) unsigned short As[3 * 256 * 64];
  __shared__ __align__(16) unsigned short Bs[3 * 128 * 64];
  const int tid = threadIdx.x, lane = tid & 63, w8 = tid >> 6;
  // XCD swizzle (bijective; nwg % 8 == 0 for all launches)
  int flat = blockIdx.x;
  const int nwg = gridDim.x;
  flat = (flat & 7) * (nwg >> 3) + (flat >> 3);
  const int m0 = (flat / nbn) * 256, n0 = (flat % nbn) * 128;
  const int NT = K >> 6;

  const int R0 = (w8 & 3) * 64, C0 = (w8 >> 2) * 64;
  const int fr = lane & 15, fg = lane >> 4;

  f32x4 acc[4][4];
#pragma unroll
  for (int i = 0; i < 4; ++i)
#pragma unroll
    for (int j = 0; j < 4; ++j)
#pragma unroll
      for (int e = 0; e < 4; ++e) acc[i][j][e] = 0.0f;

  // prologue: stage tiles 0 (buf0) and 1 (buf1): 12 calls
#pragma unroll
  for (int p = 0; p < 2; ++p) {
#pragma unroll
    for (int c = 0; c < 4; ++c)
      g2l_call(A + (long long)(m0 + c * 64) * lda + p * 64, lda,
               As + p * 16384 + c * 4096, tid);
#pragma unroll
    for (int c = 0; c < 2; ++c)
      g2l_call(Bt + (long long)(n0 + c * 64) * ldb + p * 64, ldb,
               Bs + p * 8192 + c * 4096, tid);
  }
  asm volatile("s_waitcnt vmcnt(6)" ::: "memory");  // tile 0 landed
  __builtin_amdgcn_s_barrier();
  __builtin_amdgcn_sched_barrier(0);

  int tc = 0, td = 2, ts = 2;
  for (int t = 0; t < NT; ++t) {
    const unsigned short* Ab = As + tc * 16384;
    const unsigned short* Bb = Bs + tc * 8192;
    const int ks0 = ts * 64;  // stage source k-offset (tile t+2, wrapped)
    unsigned short* Ad = As + td * 16384;
    unsigned short* Bd = Bs + td * 8192;

    // ---- phase 0: k-slice 0 ------------------------------------------
    {
      short8 af[4], bf[4];
#pragma unroll
      for (int mf = 0; mf < 4; ++mf) af[mf] = lds16(Ab, R0 + mf * 16 + fr, fg);
#pragma unroll
      for (int nf = 0; nf < 4; ++nf) bf[nf] = lds16(Bb, C0 + nf * 16 + fr, fg);
      // stage tile t+2: A calls 0..2
#pragma unroll
      for (int c = 0; c < 3; ++c)
        g2l_call(A + (long long)(m0 + c * 64) * lda + ks0, lda, Ad + c * 4096, tid);
      __builtin_amdgcn_s_setprio(1);
#pragma unroll
      for (int mf = 0; mf < 4; ++mf)
#pragma unroll
        for (int nf = 0; nf < 4; ++nf)
          acc[mf][nf] = mfma_bf16(af[mf], bf[nf], acc[mf][nf]);
      __builtin_amdgcn_s_setprio(0);
    }
    // ---- phase 1: k-slice 1 ------------------------------------------
    {
      short8 af[4], bf[4];
#pragma unroll
      for (int mf = 0; mf < 4; ++mf) af[mf] = lds16(Ab, R0 + mf * 16 + fr, 4 + fg);
#pragma unroll
      for (int nf = 0; nf < 4; ++nf) bf[nf] = lds16(Bb, C0 + nf * 16 + fr, 4 + fg);
      // stage tile t+2: A call 3, B calls 0,1
      g2l_call(A + (long long)(m0 + 192) * lda + ks0, lda, Ad + 12288, tid);
#pragma unroll
      for (int c = 0; c < 2; ++c)
        g2l_call(Bt + (long long)(n0 + c * 64) * ldb + ks0, ldb, Bd + c * 4096, tid);
      __builtin_amdgcn_s_setprio(1);
#pragma unroll
      for (int mf = 0; mf < 4; ++mf)
#pragma unroll
        for (int nf = 0; nf < 4; ++nf)
          acc[mf][nf] = mfma_bf16(af[mf], bf[nf], acc[mf][nf]);
      __builtin_amdgcn_s_setprio(0);
    }
    // tile boundary: allow t+2's 6 calls in flight, require t+1 landed
    asm volatile("s_waitcnt vmcnt(6)" ::: "memory");
    __builtin_amdgcn_s_barrier();
    __builtin_amdgcn_sched_barrier(0);
    tc = (tc == 2) ? 0 : tc + 1;
    td = (td == 2) ? 0 : td + 1;
    ts = (ts + 1 == NT) ? 0 : ts + 1;
  }

  // epilogue: C layout col = lane&15, row = (lane>>4)*4 + j
  const int rb = m0 + R0 + fg * 4;
  const int cb = n0 + C0 + fr;
#pragma unroll
  for (int mf = 0; mf < 4; ++mf) {
#pragma unroll
    for (int nf = 0; nf < 4; ++nf) {
      const int col = cb + nf * 16;
      const int row0 = rb + mf * 16;
      const float bc = bias[col];
      if (MODE == 0) {
        unsigned short* C = (unsigned short*)Cv;
#pragma unroll
        for (int j = 0; j < 4; ++j)
          C[(long long)(row0 + j) * ldc + col] = f2b(acc[mf][nf][j] + bc);
      } else {
        float* C = (float*)Cv;
#pragma unroll
        for (int j = 0; j < 4; ++j)
          C[(long long)(row0 + j) * ldc + col] = acc[mf][nf][j] + bc;
      }
    }
  }
}

// ---- 128x128 MFMA GEMM (m97 structure) — used for the small expS GEMM ---
// MODE 1: bf16 out^T = acc * scale * cmul[z]       (TRANSPOSED write)
template <int MODE>
__global__ __launch_bounds__(256) void gemm128(
    const unsigned short* __restrict__ A, long long sAz, int lda,
    const unsigned short* __restrict__ Bt, long long sBz, int ldb,
    void* __restrict__ Cv, long long sCz, int ldc,
    const float* __restrict__ bias, const float* __restrict__ cmul,
    float scale, int K) {
  __shared__ __align__(16) unsigned short As[128 * 64];
  __shared__ __align__(16) unsigned short Bs[128 * 64];
  const int tid = threadIdx.x;
  const int lane = tid & 63, w = tid >> 6;
  const int wm = (w >> 1) * 64, wn = (w & 1) * 64;
  int flat = blockIdx.y * gridDim.x + blockIdx.x;
  const int nwg = gridDim.x * gridDim.y;
  flat = (flat & 7) * (nwg >> 3) + (flat >> 3);
  const int m0 = (flat % gridDim.x) * 128, n0 = (flat / gridDim.x) * 128;
  const int z = blockIdx.z;
  A += (long long)z * sAz;
  Bt += (long long)z * sBz;

  f32x4 acc[4][4];
#pragma unroll
  for (int i = 0; i < 4; ++i)
#pragma unroll
    for (int j = 0; j < 4; ++j)
#pragma unroll
      for (int e = 0; e < 4; ++e) acc[i][j][e] = 0.0f;

  const int srow = lane >> 3;          // 0..7
  const int scol = (lane & 7) << 3;    // 0..56

  for (int k0 = 0; k0 < K; k0 += 64) {
#pragma unroll
    for (int t = 0; t < 4; ++t) {
      const int rr = w * 32 + t * 8 + srow;
      gll16(&A[(long long)(m0 + rr) * lda + k0 + scol], &As[(w * 32 + t * 8) * 64]);
      gll16(&Bt[(long long)(n0 + rr) * ldb + k0 + scol], &Bs[(w * 32 + t * 8) * 64]);
    }
    __syncthreads();
#pragma unroll
    for (int kk = 0; kk < 2; ++kk) {
      const int ko = kk * 32 + (lane >> 4) * 8;
      short8 af[4], bf[4];
#pragma unroll
      for (int mf = 0; mf < 4; ++mf)
        af[mf] = *reinterpret_cast<const short8*>(&As[(wm + mf * 16 + (lane & 15)) * 64 + ko]);
#pragma unroll
      for (int nf = 0; nf < 4; ++nf)
        bf[nf] = *reinterpret_cast<const short8*>(&Bs[(wn + nf * 16 + (lane & 15)) * 64 + ko]);
#pragma unroll
      for (int mf = 0; mf < 4; ++mf)
#pragma unroll
        for (int nf = 0; nf < 4; ++nf)
          acc[mf][nf] = mfma_bf16(af[mf], bf[nf], acc[mf][nf]);
    }
    __syncthreads();
  }

  const int rb = m0 + wm + ((lane >> 4) << 2);
  const int cb = n0 + wn + (lane & 15);
  float scl = scale;
  if (MODE == 1) scl *= cmul[z];
#pragma unroll
  for (int mf = 0; mf < 4; ++mf) {
#pragma unroll
    for (int nf = 0; nf < 4; ++nf) {
      const int col = cb + nf * 16;
      const int row0 = rb + mf * 16;
      if (MODE == 1) {
        unsigned short* C = (unsigned short*)Cv + (long long)z * sCz;
        us4 pk;
#pragma unroll
        for (int j = 0; j < 4; ++j) pk[j] = f2b(acc[mf][nf][j] * scl);
        *reinterpret_cast<us4*>(&C[(long long)col * ldc + row0]) = pk;  // C^T
      }
    }
  }
}

// ---- fused flash attention, S^T form, P fully in registers --------------
__global__ __launch_bounds__(256, 4) void attn_kernel(
    const unsigned short* __restrict__ QKVEE,
    const unsigned short* __restrict__ Vt,
    const unsigned short* __restrict__ expS,   // [b][q][k] bf16, pre-scaled
    unsigned short* __restrict__ ctx) {
  __shared__ __align__(16) unsigned short Ks[64 * 64];   // [k][d]
  __shared__ __align__(16) unsigned short Vs[64 * 64];   // [d][tok]
  __shared__ __align__(16) unsigned short Bs[64 * 64];   // [q][k]

  const int tid = threadIdx.x, lane = tid & 63, w = tid >> 6;
  const int flat = blockIdx.x;
  const int pos = flat >> 3;
  const int h = pos & 15, b = (pos >> 4) & 3;
  const int qt = (flat & 7) + 8 * (pos >> 6);
  const int qbase = qt * 64;
  const long long tb = (long long)b * SS;

  const int c0 = lane & 15, g = lane >> 4, r0 = g * 4;
  const int qr = w * 16 + c0;   // this lane's query row within the 64-q tile

  short8 qf[2];
#pragma unroll
  for (int kk = 0; kk < 2; ++kk)
    qf[kk] = *reinterpret_cast<const short8*>(
        &QKVEE[(tb + qbase + qr) * NCAT + h * HD + kk * 32 + g * 8]);

  float m = -3.0e38f, l = 0.0f;
  f32x4 acc[4];
#pragma unroll
  for (int nf = 0; nf < 4; ++nf)
#pragma unroll
    for (int j = 0; j < 4; ++j) acc[nf][j] = 0.0f;

  for (int kb = 0; kb < SS; kb += 64) {
    stage64(QKVEE + (tb + kb) * NCAT + HIDDEN + h * HD, NCAT, Ks, w, lane);
    stage64(Vt + (long long)(h * HD) * NTOK + tb + kb, NTOK, Vs, w, lane);
    stage64(expS + (tb + qbase) * SS + kb, SS, Bs, w, lane);
    __syncthreads();

    // S^T = K·Q^T
    f32x4 s[4];
#pragma unroll
    for (int nf = 0; nf < 4; ++nf)
#pragma unroll
      for (int j = 0; j < 4; ++j) s[nf][j] = 0.0f;
#pragma unroll
    for (int kk = 0; kk < 2; ++kk) {
      const int bx = kk * 4 + g;
#pragma unroll
      for (int nf = 0; nf < 4; ++nf) {
        short8 kf = lds16(Ks, nf * 16 + c0, bx);
        s[nf] = mfma_bf16(kf, qf[kk], s[nf]);
      }
    }

    float sv[4][4];
#pragma unroll
    for (int nf = 0; nf < 4; ++nf) {
      const int col = nf * 16 + r0;
      const us4 bb = *reinterpret_cast<const us4*>(
          &Bs[qr * 64 + (((col >> 3) ^ (qr & 7)) << 3) + (col & 7)]);
#pragma unroll
      for (int j = 0; j < 4; ++j) sv[nf][j] = s[nf][j] + b2f(bb[j]);
    }

    float t0 = fmaxf(fmaxf(sv[0][0], sv[0][1]), fmaxf(sv[0][2], sv[0][3]));
    float t1 = fmaxf(fmaxf(sv[1][0], sv[1][1]), fmaxf(sv[1][2], sv[1][3]));
    float t2 = fmaxf(fmaxf(sv[2][0], sv[2][1]), fmaxf(sv[2][2], sv[2][3]));
    float t3 = fmaxf(fmaxf(sv[3][0], sv[3][1]), fmaxf(sv[3][2], sv[3][3]));
    float rmax = fmaxf(fmaxf(t0, t1), fmaxf(t2, t3));
    rmax = fmaxf(rmax, __shfl_xor(rmax, 16));
    rmax = fmaxf(rmax, __shfl_xor(rmax, 32));

    if (__any(rmax > m + 8.0f)) {
      const float mn = fmaxf(m, rmax);
      const float sc = __builtin_amdgcn_exp2f(m - mn);
      m = mn;
      l *= sc;
      float scj[4];
#pragma unroll
      for (int j = 0; j < 4; ++j) scj[j] = __shfl(sc, r0 + j);
#pragma unroll
      for (int nf = 0; nf < 4; ++nf)
#pragma unroll
        for (int j = 0; j < 4; ++j) acc[nf][j] *= scj[j];
    }

    unsigned int wds[4][2];
    float ps0 = 0.f, ps1 = 0.f;
#pragma unroll
    for (int nf = 0; nf < 4; ++nf) {
      const float p0 = __builtin_amdgcn_exp2f(sv[nf][0] - m);
      const float p1 = __builtin_amdgcn_exp2f(sv[nf][1] - m);
      const float p2 = __builtin_amdgcn_exp2f(sv[nf][2] - m);
      const float p3 = __builtin_amdgcn_exp2f(sv[nf][3] - m);
      wds[nf][0] = cvt_pk(p0, p1);
      wds[nf][1] = cvt_pk(p2, p3);
      ps0 += p0 + p1;
      ps1 += p2 + p3;
    }
    float psum = ps0 + ps1;
    psum += __shfl_xor(psum, 16);
    psum += __shfl_xor(psum, 32);
    l += psum;

#pragma unroll
    for (int kk = 0; kk < 2; ++kk) {
      union { unsigned int u[4]; short8 v8; } pa;
      pa.u[0] = wds[2 * kk][0];
      pa.u[1] = wds[2 * kk][1];
      pa.u[2] = wds[2 * kk + 1][0];
      pa.u[3] = wds[2 * kk + 1][1];
#pragma unroll
      for (int nf = 0; nf < 4; ++nf) {
        const int rowd = nf * 16 + c0;
        const int cA = kk * 32 + r0;
        const int cB = cA + 16;
        union { us4 h2[2]; short8 v8; } vf;
        vf.h2[0] = *reinterpret_cast<const us4*>(
            &Vs[rowd * 64 + (((cA >> 3) ^ (rowd & 7)) << 3) + (cA & 7)]);
        vf.h2[1] = *reinterpret_cast<const us4*>(
            &Vs[rowd * 64 + (((cB >> 3) ^ (rowd & 7)) << 3) + (cB & 7)]);
        acc[nf] = mfma_bf16(pa.v8, vf.v8, acc[nf]);
      }
    }
    __syncthreads();
  }

  float linv[4];
#pragma unroll
  for (int j = 0; j < 4; ++j) linv[j] = 1.0f / __shfl(l, r0 + j);
#pragma unroll
  for (int nf = 0; nf < 4; ++nf)
#pragma unroll
    for (int j = 0; j < 4; ++j) {
      const int qrow = qbase + w * 16 + r0 + j;
      const int d = nf * 16 + c0;
      ctx[(tb + qrow) * HIDDEN + h * HD + d] = f2b(acc[nf][j] * linv[j]);
    }
}

extern "C" void kernel_launch(void* const* d_in, const int* in_sizes, int n_in,
                              void* d_out, int out_size, void* d_ws, size_t ws_size,
                              hipStream_t stream) {
  const float* x    = (const float*)d_in[0];
  const float* conf = (const float*)d_in[1];
  const float* Wq   = (const float*)d_in[2];
  const float* bq   = (const float*)d_in[3];
  const float* Wk   = (const float*)d_in[4];
  const float* bk   = (const float*)d_in[5];
  const float* Wv   = (const float*)d_in[6];
  const float* bv   = (const float*)d_in[7];
  const float* Weq  = (const float*)d_in[8];
  const float* beq  = (const float*)d_in[9];
  const float* Wek  = (const float*)d_in[10];
  const float* bek  = (const float*)d_in[11];
  const float* Wo   = (const float*)d_in[12];
  const float* bo   = (const float*)d_in[13];

  char* ws = (char*)d_ws;
  unsigned short* A1    = (unsigned short*)(ws);                               // 33,554,432 B
  unsigned short* WcatT = (unsigned short*)(ws + 33554432);                    // 14,680,064 B
  float*          bcat  = (float*)(ws + 48234496);                             //     16,384 B (padded)
  unsigned short* WoT   = (unsigned short*)(ws + 48250880);                    //  2,097,152 B
  unsigned short* QKVEE = (unsigned short*)(ws + 50348032);                    // 58,720,256 B
  unsigned short* Vt    = (unsigned short*)(ws + 109068288);                   // 16,777,216 B
  unsigned short* ctx   = (unsigned short*)(ws + 125845504);                   // 16,777,216 B
  // exp-scores [b][q][k] (bf16) lives in d_out; overwritten by final GEMM.
  unsigned short* expS  = (unsigned short*)d_out;

  prep_x<<<dim3(8192), dim3(256), 0, stream>>>(x, A1);
  bias_cat<<<dim3(14), dim3(256), 0, stream>>>(bq, bk, bv, beq, bek, bcat);
  trans_w<<<dim3(16, 16), dim3(256), 0, stream>>>(Wq, 1024, WcatT, 2048, 0, 1, QSCALE);
  trans_w<<<dim3(16, 16), dim3(256), 0, stream>>>(Wk, 1024, WcatT, 2048, 1024, 1, 1.0f);
  trans_w<<<dim3(16, 16), dim3(256), 0, stream>>>(Wv, 1024, WcatT, 2048, 2048, 1, 1.0f);
  trans_w<<<dim3(16, 4),  dim3(256), 0, stream>>>(Weq, 256, WcatT, 2048, 3072, 1, 1.0f);
  trans_w<<<dim3(16, 4),  dim3(256), 0, stream>>>(Wek, 256, WcatT, 2048, 3328, 1, 1.0f);
  trans_w<<<dim3(16, 16), dim3(256), 0, stream>>>(Wo, 1024, WoT, 1024, 0, 0, 1.0f);

  // Q|K|V|EQ|EK = [xh|xl] @ [W;W] + bias  (deep-pipelined 256x128 GEMM)
  gemm256<0><<<dim3(896), dim3(512), 0, stream>>>(
      A1, 2048, WcatT, 2048, QKVEE, NCAT, bcat, 2048, 28);

  trans_v<<<dim3(128, 16), dim3(256), 0, stream>>>(QKVEE, Vt);

  // expS[b][q][k] = ((EQ·EK^T)/16 * 0.3*conf[b]*log2e)  via C=EK·EQ^T + C^T
  gemm128<1><<<dim3(16, 16, 4), dim3(256), 0, stream>>>(
      QKVEE + 3328, (long long)SS * NCAT, NCAT,
      QKVEE + 3072, (long long)SS * NCAT, NCAT,
      expS, (long long)SS * SS, SS, nullptr, conf,
      0.3f * 1.44269504f / 16.0f, 256);

  attn_kernel<<<dim3(2048), dim3(256), 0, stream>>>(QKVEE, Vt, expS, ctx);

  // out = ctx @ Wo + bo  (f32 out, overwrites exp-scores scratch)
  gemm256<2><<<dim3(256), dim3(512), 0, stream>>>(
      ctx, 1024, WoT, 1024, d_out, 1024, bo, 1024, 8);
}